// Round 8
// baseline (643.237 us; speedup 1.0000x reference)
//
#include <hip/hip_runtime.h>

#define D_MODEL 1024
#define TSEQ    4096
#define BATCH   4
#define MROWS   (BATCH * TSEQ)   // 16384
#define KDIM    1024
#define NDIM    1024
#define EPSV    1e-6f

typedef __attribute__((ext_vector_type(8))) short short8;
typedef __attribute__((ext_vector_type(4))) float floatx4;

__device__ inline unsigned short f2bf(float f) {
  unsigned u = __float_as_uint(f);
  unsigned r = (u + 0x7FFFu + ((u >> 16) & 1u)) >> 16;  // RNE
  return (unsigned short)r;
}
__device__ inline float phi_f(float x) { return x > 0.f ? x + 1.f : __expf(x); }

// ---------------- fused prep: fp32->bf16 (x + 4 weights) + zero ksum/kvsum ----
#define NX4 4194304   // x float4 count
#define NW4 262144    // one weight float4 count
#define NZ4 2048      // ksum+kvsum float4 count

__global__ __launch_bounds__(256) void prep_kernel(
    const float* __restrict__ x,  const float* __restrict__ wq,
    const float* __restrict__ wk, const float* __restrict__ wv,
    const float* __restrict__ wg,
    unsigned short* __restrict__ xb,  unsigned short* __restrict__ wqb,
    unsigned short* __restrict__ wkb, unsigned short* __restrict__ wvb,
    unsigned short* __restrict__ wgb, float* __restrict__ zbase)
{
  long i = (long)blockIdx.x * 256 + threadIdx.x;
  const float* src; unsigned short* dst; long j = i;
  if (j < NX4) { src = x; dst = xb; }
  else {
    j -= NX4;
    if (j < NW4) { src = wq; dst = wqb; }
    else { j -= NW4;
      if (j < NW4) { src = wk; dst = wkb; }
      else { j -= NW4;
        if (j < NW4) { src = wv; dst = wvb; }
        else { j -= NW4;
          if (j < NW4) { src = wg; dst = wgb; }
          else { j -= NW4;
            if (j < NZ4) { float4 zz = {0.f,0.f,0.f,0.f}; ((float4*)zbase)[j] = zz; }
            return;
          }
        }
      }
    }
  }
  float4 f = ((const float4*)src)[j];
  ushort4 o;
  o.x = f2bf(f.x); o.y = f2bf(f.y); o.z = f2bf(f.z); o.w = f2bf(f.w);
  ((ushort4*)dst)[j] = o;
}

// ---------------- streaming GEMM (no LDS staging, no K-loop barriers) -------
// A (32 MB bf16) is L3-resident; B panels (4 MB) are L2-resident. Fragment
// loads go DIRECTLY global->VGPR: lane l reads 16B at row (fragrow + (l&15)),
// k-offset ((l>>4)*8 + kk*32 + kt). Lanes l4=0..3 of one row form one full
// 64B line -> 16 fully-used lines per load instruction. Frags double-buffered
// one K-step ahead (named sets, static indices); the compiler's per-register
// vmcnt pipelines loads under the 32-MFMA clusters. No barriers -> waves
// decorrelate, MFMA/VMEM/VALU overlap across the CU (the r2-r7 plateau was
// barrier-coupled pipes summing instead of overlapping).

// common fragment-load macros (element-unit pointers, KDIM row stride)
#define LD4(S, P, kt) { _Pragma("unroll") for (int f_ = 0; f_ < 4; ++f_) { \
    S[f_][0] = *(const short8*)((P) + (size_t)f_ * 16 * KDIM + (kt)); \
    S[f_][1] = *(const short8*)((P) + (size_t)f_ * 16 * KDIM + (kt) + 32); } }
#define LD2(S, P, kt) { _Pragma("unroll") for (int j_ = 0; j_ < 2; ++j_) { \
    S[j_][0] = *(const short8*)((P) + (size_t)j_ * 16 * KDIM + (kt)); \
    S[j_][1] = *(const short8*)((P) + (size_t)j_ * 16 * KDIM + (kt) + 32); } }

// ---------------- phase 1: k/v GEMM with in-register fused reduction --------
// 256 thr / 4 waves; wave (wm,wn): rows bm*128+wm*64 (64), cols bn*64+wn*32
// (32), DUAL k+v accumulators (A frags shared). Grid 2048 = 16 bn x 128 bm.
__global__ __launch_bounds__(256, 2) void gemm_kv_kernel(
    const unsigned short* __restrict__ A,
    const unsigned short* __restrict__ Wk, const unsigned short* __restrict__ Wv,
    float* __restrict__ ksum, float* __restrict__ kvsum)
{
  // XCD swizzle: same-bn blocks grouped per XCD (B panels L2-resident)
  const int bid = blockIdx.x;
  const int sw  = (bid & 7) * 256 + (bid >> 3);
  const int bn  = sw >> 7;    // 0..15
  const int bm  = sw & 127;   // 0..127

  const int tid  = threadIdx.x;
  const int lane = tid & 63;
  const int w    = tid >> 6;  // 0..3
  const int wm   = w >> 1;    // 0..1
  const int wn   = w & 1;     // 0..1
  const int la   = lane & 15;
  const int l4   = lane >> 4;

  floatx4 ak[4][2], av[4][2];
#pragma unroll
  for (int i = 0; i < 4; i++)
#pragma unroll
    for (int j = 0; j < 2; j++) {
      floatx4 zz = {0.f,0.f,0.f,0.f}; ak[i][j] = zz; av[i][j] = zz;
    }

  const unsigned short* Ab = A  + (size_t)(bm * 128 + wm * 64 + la) * KDIM + l4 * 8;
  const unsigned short* Kb = Wk + (size_t)(bn * 64 + wn * 32 + la) * KDIM + l4 * 8;
  const unsigned short* Vb = Wv + (size_t)(bn * 64 + wn * 32 + la) * KDIM + l4 * 8;

  short8 a0[4][2], a1[4][2], k0[2][2], k1[2][2], v0[2][2], v1[2][2];

#define FMA_KV(SA, SK, SV) { _Pragma("unroll") for (int f_ = 0; f_ < 4; ++f_) \
    _Pragma("unroll") for (int j_ = 0; j_ < 2; ++j_) \
    _Pragma("unroll") for (int kk_ = 0; kk_ < 2; ++kk_) { \
      ak[f_][j_] = __builtin_amdgcn_mfma_f32_16x16x32_bf16( \
          SA[f_][kk_], SK[j_][kk_], ak[f_][j_], 0, 0, 0); \
      av[f_][j_] = __builtin_amdgcn_mfma_f32_16x16x32_bf16( \
          SA[f_][kk_], SV[j_][kk_], av[f_][j_], 0, 0, 0); } }

  LD4(a0, Ab, 0); LD2(k0, Kb, 0); LD2(v0, Vb, 0);
  for (int kt = 0; kt < KDIM; kt += 128) {
    LD4(a1, Ab, kt + 64); LD2(k1, Kb, kt + 64); LD2(v1, Vb, kt + 64);
    FMA_KV(a0, k0, v0);
    if (kt + 128 < KDIM) {
      LD4(a0, Ab, kt + 128); LD2(k0, Kb, kt + 128); LD2(v0, Vb, kt + 128);
    }
    FMA_KV(a1, k1, v1);
  }

  // ---- fused column reduction (per-lane over own 16 rows, then row-quads) --
  const int b = bm >> 5;               // 32 bm-blocks (128 rows) per batch
  float kp[2] = {0.f, 0.f};
  float vp[2] = {0.f, 0.f};
#pragma unroll
  for (int j = 0; j < 2; j++)
#pragma unroll
    for (int f = 0; f < 4; f++)
#pragma unroll
      for (int r = 0; r < 4; r++) {
        float kk = phi_f(ak[f][j][r]);
        kp[j] += kk;
        vp[j] += kk * av[f][j][r];
      }
#pragma unroll
  for (int j = 0; j < 2; j++) {
    kp[j] += __shfl_xor(kp[j], 16, 64); kp[j] += __shfl_xor(kp[j], 32, 64);
    vp[j] += __shfl_xor(vp[j], 16, 64); vp[j] += __shfl_xor(vp[j], 32, 64);
  }
  if (lane < 16) {
#pragma unroll
    for (int j = 0; j < 2; j++) {
      int col = bn * 64 + wn * 32 + j * 16 + lane;
      atomicAdd(ksum  + (size_t)b * D_MODEL + col, kp[j]);
      atomicAdd(kvsum + (size_t)b * D_MODEL + col, vp[j]);
    }
  }
#undef FMA_KV
}

// ---------------- phase 2: q/g GEMM with fused finalize ---------------------
// 512 thr / 8 waves; wave (wm 0..3, is_g): rows bm*256+wm*64 (64), cols
// bn*64..+64 (= exactly head bn). q-wave reduces s,z in-wave, passes o via
// o_lds to its g-partner (one __syncthreads, outside the K-loop).
// Grid 1024 = 16 bn x 64 bm.
__global__ __launch_bounds__(512, 2) void gemm_qg_kernel(
    const unsigned short* __restrict__ A,
    const unsigned short* __restrict__ Wq, const unsigned short* __restrict__ Wg,
    const float* __restrict__ x, const float* __restrict__ bg,
    const float* __restrict__ ksum, const float* __restrict__ kvsum,
    float* __restrict__ out)
{
  __shared__ float o_lds[256];         // o per block row

  const int bid = blockIdx.x;
  const int sw  = (bid & 7) * 128 + (bid >> 3);
  const int bn  = sw >> 6;    // 0..15 (= head index)
  const int bm  = sw & 63;    // 0..63

  const int tid  = threadIdx.x;
  const int lane = tid & 63;
  const int w    = tid >> 6;  // 0..7
  const int wm   = w >> 1;    // 0..3
  const int is_g = w & 1;
  const int la   = lane & 15;
  const int l4   = lane >> 4;
  const int wr   = wm * 64;

  floatx4 acc[4][4];
#pragma unroll
  for (int i = 0; i < 4; i++)
#pragma unroll
    for (int j = 0; j < 4; j++) { floatx4 zz = {0.f,0.f,0.f,0.f}; acc[i][j] = zz; }

  const unsigned short* Ab = A + (size_t)(bm * 256 + wr + la) * KDIM + l4 * 8;
  const unsigned short* Wsel = is_g ? Wg : Wq;
  const unsigned short* Bb = Wsel + (size_t)(bn * 64 + la) * KDIM + l4 * 8;

  short8 a0[4][2], a1[4][2], b0[4][2], b1[4][2];

#define FMA_QG(SA, SB) { _Pragma("unroll") for (int f_ = 0; f_ < 4; ++f_) \
    _Pragma("unroll") for (int j_ = 0; j_ < 4; ++j_) \
    _Pragma("unroll") for (int kk_ = 0; kk_ < 2; ++kk_) { \
      acc[f_][j_] = __builtin_amdgcn_mfma_f32_16x16x32_bf16( \
          SA[f_][kk_], SB[j_][kk_], acc[f_][j_], 0, 0, 0); } }

  LD4(a0, Ab, 0); LD4(b0, Bb, 0);
  for (int kt = 0; kt < KDIM; kt += 128) {
    LD4(a1, Ab, kt + 64); LD4(b1, Bb, kt + 64);
    FMA_QG(a0, b0);
    if (kt + 128 < KDIM) { LD4(a0, Ab, kt + 128); LD4(b0, Bb, kt + 128); }
    FMA_QG(a1, b1);
  }

  // ---- fused finalize ----
  const int b  = bm >> 4;              // 16 bm-blocks (256 rows) per batch
  const int ro = l4 * 4;
  const int co = la;

  if (!is_g) {
    float kvv[4], ksv[4];
#pragma unroll
    for (int j = 0; j < 4; j++) {
      int col = bn * 64 + j * 16 + co;
      kvv[j] = kvsum[(size_t)b * D_MODEL + col];
      ksv[j] = ksum [(size_t)b * D_MODEL + col];
    }
#pragma unroll
    for (int f = 0; f < 4; f++)
#pragma unroll
      for (int r = 0; r < 4; r++) {
        float s = 0.f, z = 0.f;
#pragma unroll
        for (int j = 0; j < 4; j++) {
          float qq = phi_f(acc[f][j][r]);
          s += qq * kvv[j]; z += qq * ksv[j];
        }
#pragma unroll
        for (int m = 1; m < 16; m <<= 1) {  // sum cols across 16-lane group
          s += __shfl_xor(s, m, 64);
          z += __shfl_xor(z, m, 64);
        }
        if (co == 0) o_lds[wr + f * 16 + ro + r] = s / (z + EPSV);
      }
  }
  __syncthreads();
  if (is_g) {
    float bgv[4];
#pragma unroll
    for (int j = 0; j < 4; j++) bgv[j] = bg[bn * 64 + j * 16 + co];
#pragma unroll
    for (int f = 0; f < 4; f++)
#pragma unroll
      for (int r = 0; r < 4; r++) {
        int rowl = wr + f * 16 + ro + r;
        int grow = bm * 256 + rowl;
        float ov = o_lds[rowl];
#pragma unroll
        for (int j = 0; j < 4; j++) {
          int gcol = bn * 64 + j * 16 + co;
          float gt = 1.f / (1.f + __expf(-(acc[f][j][r] + bgv[j])));
          float xv = x[(size_t)grow * D_MODEL + gcol];
          out[(size_t)grow * D_MODEL + gcol] = gt * ov + (1.f - gt) * xv;
        }
      }
  }
#undef FMA_QG
}

extern "C" void kernel_launch(void* const* d_in, const int* in_sizes, int n_in,
                              void* d_out, int out_size, void* d_ws, size_t ws_size,
                              hipStream_t stream) {
  (void)in_sizes; (void)n_in; (void)out_size; (void)ws_size;
  const float* x  = (const float*)d_in[0];
  const float* Wq = (const float*)d_in[1];
  const float* Wk = (const float*)d_in[2];
  const float* Wv = (const float*)d_in[3];
  /* d_in[4] = Wo — unused by the reference */
  const float* Wg = (const float*)d_in[5];
  const float* bg = (const float*)d_in[6];
  float* out = (float*)d_out;

  char* ws = (char*)d_ws;
  const size_t xel = (size_t)MROWS * D_MODEL;
  const size_t wel = (size_t)NDIM * KDIM;
  unsigned short* xbf = (unsigned short*)ws; ws += xel * 2;
  unsigned short* wqb = (unsigned short*)ws; ws += wel * 2;
  unsigned short* wkb = (unsigned short*)ws; ws += wel * 2;
  unsigned short* wvb = (unsigned short*)ws; ws += wel * 2;
  unsigned short* wgb = (unsigned short*)ws; ws += wel * 2;
  float* ksum  = (float*)ws; ws += (size_t)BATCH * D_MODEL * 4;  // contiguous
  float* kvsum = (float*)ws; ws += (size_t)BATCH * D_MODEL * 4;

  // 1) fused converts + zero
  const long total4 = (long)NX4 + 4L * NW4 + NZ4;
  prep_kernel<<<(int)((total4 + 255) / 256), 256, 0, stream>>>(
      x, Wq, Wk, Wv, Wg, xbf, wqb, wkb, wvb, wgb, ksum);

  // 2) phase 1: k/v with fused reduction (2048 blocks = 16 bn x 128 bm)
  gemm_kv_kernel<<<2048, 256, 0, stream>>>(xbf, wkb, wvb, ksum, kvsum);

  // 3) phase 2: q/g with fused finalize (1024 blocks = 16 bn x 64 bm)
  gemm_qg_kernel<<<1024, 512, 0, stream>>>(xbf, wqb, wgb, x, bg, ksum, kvsum, out);
}